// Round 10
// baseline (212.968 us; speedup 1.0000x reference)
//
#include <hip/hip_runtime.h>
#include <hip/hip_bf16.h>
#include <hip/hip_cooperative_groups.h>
#include <stdint.h>

namespace cg = cooperative_groups;

#define IN_FEATS 128
#define TWO_IN   256
#define HIDDEN   128
#define TILE_M   64
#define GEMM_BLOCKS 256

typedef __attribute__((ext_vector_type(8))) __bf16 bf16x8;
typedef __attribute__((ext_vector_type(8))) ushort u16x8;
typedef __attribute__((ext_vector_type(4))) float f32x4;

__device__ __forceinline__ float bf_lo(uint32_t u) { return __uint_as_float(u << 16); }
__device__ __forceinline__ float bf_hi(uint32_t u) { return __uint_as_float(u & 0xffff0000u); }
__device__ __forceinline__ ushort f2bf(float f) {
  uint32_t u = __float_as_uint(f);
  uint32_t r = (u + 0x7fffu + ((u >> 16) & 1u)) >> 16;  // RNE
  return (ushort)r;
}

// ---------------- fused: persistent pipelined GEMM -> grid sync -> edge ----------------
// Phase 1 (R8-proven body): P[M][256] = bf16(h)[M][128] @ bf16(W1cat)[256][128]^T + 0.5*b1
//   256 blocks x 1024 thr (16 waves, 4x4), W1 fp32->LDS B staged per block,
//   A double-buffer + reg-prefetch, 129KB LDS -> 1 block/CU (all 256 co-resident).
// grid.sync() (device-scope ordering; P visible across XCDs)
// Phase 2 (R2-form): 16 lanes/edge, 4 edges/wave, grid-stride over 4096 waves.
__global__ __launch_bounds__(1024)
void fused_kernel(const float* __restrict__ h, const float* __restrict__ W1,
                  const float* __restrict__ b1, ushort* __restrict__ P,
                  const int* __restrict__ src, const int* __restrict__ dst,
                  const float* __restrict__ W2, const float* __restrict__ b2,
                  float* __restrict__ out, int M, int nTiles, int nE) {
  __shared__ __align__(16) char ldsraw[132096];
  // layout: A0 16KB | A1 16KB | outLds 33792B | B 64KB   (disjoint, no aliasing)
  char* ldsA0    = ldsraw;
  char* ldsA1    = ldsraw + 16384;
  ushort* outLds = (ushort*)(ldsraw + 32768);       // 64 rows x 264 shorts
  char* ldsB     = ldsraw + 66560;

  const int tid  = threadIdx.x;      // 0..1023
  const int lane = tid & 63;
  const int w    = tid >> 6;         // 0..15

  // --- stage B: W1 fp32 -> bf16, swizzled ds_write (fused cvt_w1) ---
  #pragma unroll
  for (int it = 0; it < 4; ++it) {
    int idx = it * 1024 + tid;              // 8-elem chunk id, 0..4095
    int row = idx >> 4;                     // 0..255
    int c   = idx & 15;                     // chunk of 8 floats
    const float* srcp = (row < HIDDEN) ? (W1 + row * TWO_IN + c * 8)
                                       : (W1 + (row - HIDDEN) * TWO_IN + IN_FEATS + c * 8);
    float4 v0 = *(const float4*)(srcp);
    float4 v1 = *(const float4*)(srcp + 4);
    u16x8 o;
    o[0] = f2bf(v0.x); o[1] = f2bf(v0.y); o[2] = f2bf(v0.z); o[3] = f2bf(v0.w);
    o[4] = f2bf(v1.x); o[5] = f2bf(v1.y); o[6] = f2bf(v1.z); o[7] = f2bf(v1.w);
    *(u16x8*)(ldsB + row * 256 + ((c * 16) ^ ((row & 7) << 4))) = o;
  }

  // --- stage A for first tile into A0 ---
  {
    int m0 = blockIdx.x * TILE_M;
    int row = tid >> 4;                     // 64 rows x 16 chunks = 1024
    int c   = tid & 15;
    int grow = m0 + row;
    float4 v0 = {0, 0, 0, 0}, v1 = {0, 0, 0, 0};
    if (grow < M) {
      const float* srcp = h + (size_t)grow * IN_FEATS + c * 8;
      v0 = *(const float4*)(srcp);
      v1 = *(const float4*)(srcp + 4);
    }
    u16x8 o;
    o[0] = f2bf(v0.x); o[1] = f2bf(v0.y); o[2] = f2bf(v0.z); o[3] = f2bf(v0.w);
    o[4] = f2bf(v1.x); o[5] = f2bf(v1.y); o[6] = f2bf(v1.z); o[7] = f2bf(v1.w);
    *(u16x8*)(ldsA0 + row * 256 + ((c * 16) ^ ((row & 7) << 4))) = o;
  }
  __syncthreads();   // B + A0 staged

  const int wr = w >> 2, wc = w & 3;        // wave tile: 16 rows x 64 cols

  // bias fold: P += 0.5*b1[col & 127]
  float bias[4];
  #pragma unroll
  for (int n = 0; n < 4; ++n) {
    int col = wc * 64 + n * 16 + (lane & 15);
    bias[n] = 0.5f * b1[col & 127];
  }

  int cur = 0;
  for (int t = blockIdx.x; t < nTiles; t += GEMM_BLOCKS) {
    const int m0 = t * TILE_M;
    const int tn = t + GEMM_BLOCKS;
    const bool pf = (tn < nTiles);
    char* ldsAcur = cur ? ldsA1 : ldsA0;
    char* ldsAnxt = cur ? ldsA0 : ldsA1;

    // --- issue prefetch loads for tile t+GEMM_BLOCKS (fp32 -> regs, no wait) ---
    const int prow = tid >> 4;
    const int pc   = tid & 15;
    float4 p0 = {0, 0, 0, 0}, p1 = {0, 0, 0, 0};
    if (pf) {
      int grow = tn * TILE_M + prow;
      if (grow < M) {
        const float* srcp = h + (size_t)grow * IN_FEATS + pc * 8;
        p0 = *(const float4*)(srcp);
        p1 = *(const float4*)(srcp + 4);
      }
    }

    // --- MFMA on A[cur], B ---
    f32x4 acc[4] = {};
    #pragma unroll
    for (int kk = 0; kk < 4; ++kk) {
      bf16x8 af, bfr[4];
      const int kb = kk * 64 + ((lane >> 4) << 4);
      {
        int row = wr * 16 + (lane & 15);
        af = *(const bf16x8*)(ldsAcur + row * 256 + (kb ^ ((row & 7) << 4)));
      }
      #pragma unroll
      for (int n = 0; n < 4; ++n) {
        int row = wc * 64 + n * 16 + (lane & 15);
        bfr[n] = *(const bf16x8*)(ldsB + row * 256 + (kb ^ ((row & 7) << 4)));
      }
      #pragma unroll
      for (int n = 0; n < 4; ++n)
        acc[n] = __builtin_amdgcn_mfma_f32_16x16x32_bf16(af, bfr[n], acc[n], 0, 0, 0);
    }

    __syncthreads();  // B1: prior iter's store-phase finished reading outLds

    // --- acc + bias -> outLds (bf16) ---
    #pragma unroll
    for (int n = 0; n < 4; ++n) {
      int col = wc * 64 + n * 16 + (lane & 15);
      #pragma unroll
      for (int r = 0; r < 4; ++r) {
        int row = wr * 16 + ((lane >> 4) << 2) + r;
        outLds[row * 264 + col] = f2bf(acc[n][r] + bias[n]);
      }
    }

    // --- convert prefetched A and write to the other buffer ---
    if (pf) {
      u16x8 o;
      o[0] = f2bf(p0.x); o[1] = f2bf(p0.y); o[2] = f2bf(p0.z); o[3] = f2bf(p0.w);
      o[4] = f2bf(p1.x); o[5] = f2bf(p1.y); o[6] = f2bf(p1.z); o[7] = f2bf(p1.w);
      *(u16x8*)(ldsAnxt + prow * 256 + ((pc * 16) ^ ((prow & 7) << 4))) = o;
    }

    __syncthreads();  // B2: outLds + A[next] writes visible

    // --- outLds -> P global stores (tile t) ---
    const int mleft = M - m0;
    #pragma unroll
    for (int it = 0; it < 2; ++it) {
      int idx = it * 1024 + tid;            // 16B chunk, 0..2047
      int row = idx >> 5;                   // 32 chunks per 512B row
      int c   = idx & 31;
      if (row < mleft)
        *(u16x8*)((char*)P + (size_t)(m0 + row) * 512 + c * 16) =
            *(const u16x8*)(outLds + row * 264 + c * 8);
    }
    cur ^= 1;
  }

  // ================= grid-wide sync: all P visible, device scope =================
  cg::this_grid().sync();

  // ================= phase 2: edge (R2-form, 16 lanes/edge, 4 edges/wave) ========
  const int t16 = lane & 15;        // sublane: feats [t16*8, t16*8+8)
  const int g   = lane >> 4;        // edge slot within wave
  const int wid = blockIdx.x * 16 + w;
  const int nw  = GEMM_BLOCKS * 16; // 4096 waves
  const float4 w2a = ((const float4*)W2)[2 * t16];
  const float4 w2b = ((const float4*)W2)[2 * t16 + 1];
  const float b2s = *b2;

  #pragma unroll 2
  for (int e0 = wid * 4; e0 < nE; e0 += nw * 4) {
    int e = e0 + g;
    bool valid = e < nE;
    int ec = valid ? e : nE - 1;
    int s = src[ec], d = dst[ec];
    uint4 pa = *(const uint4*)(P + (size_t)s * 256 + t16 * 8);
    uint4 pb = *(const uint4*)(P + (size_t)d * 256 + 128 + t16 * 8);
    float acc;
    acc = fmaxf(bf_lo(pa.x) + bf_lo(pb.x), 0.0f) * w2a.x;
    acc = fmaf(fmaxf(bf_hi(pa.x) + bf_hi(pb.x), 0.0f), w2a.y, acc);
    acc = fmaf(fmaxf(bf_lo(pa.y) + bf_lo(pb.y), 0.0f), w2a.z, acc);
    acc = fmaf(fmaxf(bf_hi(pa.y) + bf_hi(pb.y), 0.0f), w2a.w, acc);
    acc = fmaf(fmaxf(bf_lo(pa.z) + bf_lo(pb.z), 0.0f), w2b.x, acc);
    acc = fmaf(fmaxf(bf_hi(pa.z) + bf_hi(pb.z), 0.0f), w2b.y, acc);
    acc = fmaf(fmaxf(bf_lo(pa.w) + bf_lo(pb.w), 0.0f), w2b.z, acc);
    acc = fmaf(fmaxf(bf_hi(pa.w) + bf_hi(pb.w), 0.0f), w2b.w, acc);
    acc += __shfl_xor(acc, 8);
    acc += __shfl_xor(acc, 4);
    acc += __shfl_xor(acc, 2);
    acc += __shfl_xor(acc, 1);
    if (t16 == 0 && valid) out[e] = 1.0f / (1.0f + __expf(-(acc + b2s)));
  }
}

extern "C" void kernel_launch(void* const* d_in, const int* in_sizes, int n_in,
                              void* d_out, int out_size, void* d_ws, size_t ws_size,
                              hipStream_t stream) {
  const int*   src = (const int*)d_in[0];
  const int*   dst = (const int*)d_in[1];
  const float* h   = (const float*)d_in[2];
  const float* W1  = (const float*)d_in[3];
  const float* b1  = (const float*)d_in[4];
  const float* W2  = (const float*)d_in[5];
  const float* b2  = (const float*)d_in[6];
  float* out = (float*)d_out;
  int nE = in_sizes[0];
  int nN = in_sizes[2] / IN_FEATS;
  int nTiles = (nN + TILE_M - 1) / TILE_M;

  ushort* P = (ushort*)d_ws;                      // nN*512 B  (~51.2MB)

  void* args[] = {(void*)&h, (void*)&W1, (void*)&b1, (void*)&P,
                  (void*)&src, (void*)&dst, (void*)&W2, (void*)&b2,
                  (void*)&out, (void*)&nN, (void*)&nTiles, (void*)&nE};
  hipLaunchCooperativeKernel((void*)fused_kernel, dim3(GEMM_BLOCKS), dim3(1024),
                             args, 0, stream);
}

// Round 12
// 169.189 us; speedup vs baseline: 1.2588x; 1.2588x over previous
//
#include <hip/hip_runtime.h>
#include <hip/hip_bf16.h>
#include <stdint.h>

#define IN_FEATS 128
#define TWO_IN   256
#define HIDDEN   128
#define TILE_M   64
#define GEMM_BLOCKS 256

typedef __attribute__((ext_vector_type(8))) __bf16 bf16x8;
typedef __attribute__((ext_vector_type(8))) ushort u16x8;
typedef __attribute__((ext_vector_type(4))) float f32x4;
typedef __attribute__((ext_vector_type(4))) unsigned int u32x4;

__device__ __forceinline__ float bf_lo(uint32_t u) { return __uint_as_float(u << 16); }
__device__ __forceinline__ float bf_hi(uint32_t u) { return __uint_as_float(u & 0xffff0000u); }
__device__ __forceinline__ ushort f2bf(float f) {
  uint32_t u = __float_as_uint(f);
  uint32_t r = (u + 0x7fffu + ((u >> 16) & 1u)) >> 16;  // RNE
  return (ushort)r;
}

// ---------------- persistent pipelined GEMM, W1-conversion fused (R8 measured-best) ----
// P[M][256] = bf16(h)[M][128] @ bf16(W1cat)[256][128]^T + 0.5*b1
__global__ __launch_bounds__(1024)
void gemm_pipe_kernel(const float* __restrict__ h, const float* __restrict__ W1,
                      const float* __restrict__ b1, ushort* __restrict__ P,
                      int M, int nTiles) {
  __shared__ __align__(16) char ldsraw[132096];
  // layout: A0 16KB | A1 16KB | outLds 33792B | B 64KB   (disjoint, no aliasing)
  char* ldsA0    = ldsraw;
  char* ldsA1    = ldsraw + 16384;
  ushort* outLds = (ushort*)(ldsraw + 32768);       // 64 rows x 264 shorts
  char* ldsB     = ldsraw + 66560;

  const int tid  = threadIdx.x;      // 0..1023
  const int lane = tid & 63;
  const int w    = tid >> 6;         // 0..15

  // --- stage B: W1 fp32 -> bf16, swizzled ds_write (fused cvt_w1) ---
  #pragma unroll
  for (int it = 0; it < 4; ++it) {
    int idx = it * 1024 + tid;              // 8-elem chunk id, 0..4095
    int row = idx >> 4;                     // 0..255
    int c   = idx & 15;                     // chunk of 8 floats
    const float* srcp = (row < HIDDEN) ? (W1 + row * TWO_IN + c * 8)
                                       : (W1 + (row - HIDDEN) * TWO_IN + IN_FEATS + c * 8);
    float4 v0 = *(const float4*)(srcp);
    float4 v1 = *(const float4*)(srcp + 4);
    u16x8 o;
    o[0] = f2bf(v0.x); o[1] = f2bf(v0.y); o[2] = f2bf(v0.z); o[3] = f2bf(v0.w);
    o[4] = f2bf(v1.x); o[5] = f2bf(v1.y); o[6] = f2bf(v1.z); o[7] = f2bf(v1.w);
    *(u16x8*)(ldsB + row * 256 + ((c * 16) ^ ((row & 7) << 4))) = o;
  }

  // --- stage A for first tile into A0 ---
  {
    int m0 = blockIdx.x * TILE_M;
    int row = tid >> 4;                     // 64 rows x 16 chunks = 1024
    int c   = tid & 15;
    int grow = m0 + row;
    float4 v0 = {0, 0, 0, 0}, v1 = {0, 0, 0, 0};
    if (grow < M) {
      const float* srcp = h + (size_t)grow * IN_FEATS + c * 8;
      v0 = *(const float4*)(srcp);
      v1 = *(const float4*)(srcp + 4);
    }
    u16x8 o;
    o[0] = f2bf(v0.x); o[1] = f2bf(v0.y); o[2] = f2bf(v0.z); o[3] = f2bf(v0.w);
    o[4] = f2bf(v1.x); o[5] = f2bf(v1.y); o[6] = f2bf(v1.z); o[7] = f2bf(v1.w);
    *(u16x8*)(ldsA0 + row * 256 + ((c * 16) ^ ((row & 7) << 4))) = o;
  }
  __syncthreads();   // B + A0 staged

  const int wr = w >> 2, wc = w & 3;        // wave tile: 16 rows x 64 cols

  // bias fold: P += 0.5*b1[col & 127]
  float bias[4];
  #pragma unroll
  for (int n = 0; n < 4; ++n) {
    int col = wc * 64 + n * 16 + (lane & 15);
    bias[n] = 0.5f * b1[col & 127];
  }

  int cur = 0;
  for (int t = blockIdx.x; t < nTiles; t += GEMM_BLOCKS) {
    const int m0 = t * TILE_M;
    const int tn = t + GEMM_BLOCKS;
    const bool pf = (tn < nTiles);
    char* ldsAcur = cur ? ldsA1 : ldsA0;
    char* ldsAnxt = cur ? ldsA0 : ldsA1;

    // --- issue prefetch loads for tile t+GEMM_BLOCKS (fp32 -> regs, no wait) ---
    const int prow = tid >> 4;
    const int pc   = tid & 15;
    float4 p0 = {0, 0, 0, 0}, p1 = {0, 0, 0, 0};
    if (pf) {
      int grow = tn * TILE_M + prow;
      if (grow < M) {
        const float* srcp = h + (size_t)grow * IN_FEATS + pc * 8;
        p0 = *(const float4*)(srcp);
        p1 = *(const float4*)(srcp + 4);
      }
    }

    // --- MFMA on A[cur], B ---
    f32x4 acc[4] = {};
    #pragma unroll
    for (int kk = 0; kk < 4; ++kk) {
      bf16x8 af, bfr[4];
      const int kb = kk * 64 + ((lane >> 4) << 4);
      {
        int row = wr * 16 + (lane & 15);
        af = *(const bf16x8*)(ldsAcur + row * 256 + (kb ^ ((row & 7) << 4)));
      }
      #pragma unroll
      for (int n = 0; n < 4; ++n) {
        int row = wc * 64 + n * 16 + (lane & 15);
        bfr[n] = *(const bf16x8*)(ldsB + row * 256 + (kb ^ ((row & 7) << 4)));
      }
      #pragma unroll
      for (int n = 0; n < 4; ++n)
        acc[n] = __builtin_amdgcn_mfma_f32_16x16x32_bf16(af, bfr[n], acc[n], 0, 0, 0);
    }

    __syncthreads();  // B1: prior iter's store-phase finished reading outLds

    // --- acc + bias -> outLds (bf16) ---
    #pragma unroll
    for (int n = 0; n < 4; ++n) {
      int col = wc * 64 + n * 16 + (lane & 15);
      #pragma unroll
      for (int r = 0; r < 4; ++r) {
        int row = wr * 16 + ((lane >> 4) << 2) + r;
        outLds[row * 264 + col] = f2bf(acc[n][r] + bias[n]);
      }
    }

    // --- convert prefetched A and write to the other buffer ---
    if (pf) {
      u16x8 o;
      o[0] = f2bf(p0.x); o[1] = f2bf(p0.y); o[2] = f2bf(p0.z); o[3] = f2bf(p0.w);
      o[4] = f2bf(p1.x); o[5] = f2bf(p1.y); o[6] = f2bf(p1.z); o[7] = f2bf(p1.w);
      *(u16x8*)(ldsAnxt + prow * 256 + ((pc * 16) ^ ((prow & 7) << 4))) = o;
    }

    __syncthreads();  // B2: outLds + A[next] writes visible

    // --- outLds -> P global stores (tile t) ---
    const int mleft = M - m0;
    #pragma unroll
    for (int it = 0; it < 2; ++it) {
      int idx = it * 1024 + tid;            // 16B chunk, 0..2047
      int row = idx >> 5;                   // 32 chunks per 512B row
      int c   = idx & 31;
      if (row < mleft)
        *(u16x8*)((char*)P + (size_t)(m0 + row) * 512 + c * 16) =
            *(const u16x8*)(outLds + row * 264 + c * 8);
    }
    cur ^= 1;
  }
}

// ---------------- edge phase: 16 lanes/edge, 4 edges/wave (R2/R8 measured-best form) ----
// nontemporal hint on P gathers: no L1 reuse for random 256B gathers.
__global__ __launch_bounds__(256)
void edge_kernel(const int* __restrict__ src, const int* __restrict__ dst,
                 const ushort* __restrict__ P,
                 const float* __restrict__ W2, const float* __restrict__ b2,
                 float* __restrict__ out, int nE) {
  const int lane = threadIdx.x & 63;
  const int t = lane & 15;          // sublane: feats [t*8, t*8+8)
  const int g = lane >> 4;          // edge slot within wave
  const int wid = blockIdx.x * (blockDim.x >> 6) + (threadIdx.x >> 6);
  const int nw  = gridDim.x * (blockDim.x >> 6);
  const float4 w2a = ((const float4*)W2)[2 * t];
  const float4 w2b = ((const float4*)W2)[2 * t + 1];
  const float b2s = *b2;

  #pragma unroll 2
  for (int e0 = wid * 4; e0 < nE; e0 += nw * 4) {
    int e = e0 + g;
    bool valid = e < nE;
    int ec = valid ? e : nE - 1;
    int s = src[ec], d = dst[ec];
    u32x4 pa = __builtin_nontemporal_load((const u32x4*)(P + (size_t)s * 256 + t * 8));
    u32x4 pb = __builtin_nontemporal_load((const u32x4*)(P + (size_t)d * 256 + 128 + t * 8));
    float acc;
    acc = fmaxf(bf_lo(pa[0]) + bf_lo(pb[0]), 0.0f) * w2a.x;
    acc = fmaf(fmaxf(bf_hi(pa[0]) + bf_hi(pb[0]), 0.0f), w2a.y, acc);
    acc = fmaf(fmaxf(bf_lo(pa[1]) + bf_lo(pb[1]), 0.0f), w2a.z, acc);
    acc = fmaf(fmaxf(bf_hi(pa[1]) + bf_hi(pb[1]), 0.0f), w2a.w, acc);
    acc = fmaf(fmaxf(bf_lo(pa[2]) + bf_lo(pb[2]), 0.0f), w2b.x, acc);
    acc = fmaf(fmaxf(bf_hi(pa[2]) + bf_hi(pb[2]), 0.0f), w2b.y, acc);
    acc = fmaf(fmaxf(bf_lo(pa[3]) + bf_lo(pb[3]), 0.0f), w2b.z, acc);
    acc = fmaf(fmaxf(bf_hi(pa[3]) + bf_hi(pb[3]), 0.0f), w2b.w, acc);
    acc += __shfl_xor(acc, 8);
    acc += __shfl_xor(acc, 4);
    acc += __shfl_xor(acc, 2);
    acc += __shfl_xor(acc, 1);
    if (t == 0 && valid) out[e] = 1.0f / (1.0f + __expf(-(acc + b2s)));
  }
}

extern "C" void kernel_launch(void* const* d_in, const int* in_sizes, int n_in,
                              void* d_out, int out_size, void* d_ws, size_t ws_size,
                              hipStream_t stream) {
  const int*   src = (const int*)d_in[0];
  const int*   dst = (const int*)d_in[1];
  const float* h   = (const float*)d_in[2];
  const float* W1  = (const float*)d_in[3];
  const float* b1  = (const float*)d_in[4];
  const float* W2  = (const float*)d_in[5];
  const float* b2  = (const float*)d_in[6];
  float* out = (float*)d_out;
  const int nE = in_sizes[0];
  const int nN = in_sizes[2] / IN_FEATS;
  const int nTiles = (nN + TILE_M - 1) / TILE_M;

  ushort* P = (ushort*)d_ws;                      // nN*512 B  (~51.2MB)

  hipLaunchKernelGGL(gemm_pipe_kernel, dim3(GEMM_BLOCKS), dim3(1024), 0, stream, h, W1, b1, P, nN, nTiles);
  hipLaunchKernelGGL(edge_kernel, dim3(4096), dim3(256), 0, stream, src, dst, P, W2, b2, out, nE);
}

// Round 13
// 153.285 us; speedup vs baseline: 1.3894x; 1.1038x over previous
//
#include <hip/hip_runtime.h>
#include <hip/hip_bf16.h>
#include <stdint.h>

#define IN_FEATS 128
#define TWO_IN   256
#define HIDDEN   128
#define TILE_M   64
#define GEMM_BLOCKS 256

typedef __attribute__((ext_vector_type(8))) __bf16 bf16x8;
typedef __attribute__((ext_vector_type(8))) ushort u16x8;
typedef __attribute__((ext_vector_type(4))) float f32x4;

__device__ __forceinline__ float bf_lo(uint32_t u) { return __uint_as_float(u << 16); }
__device__ __forceinline__ float bf_hi(uint32_t u) { return __uint_as_float(u & 0xffff0000u); }
__device__ __forceinline__ ushort f2bf(float f) {
  uint32_t u = __float_as_uint(f);
  uint32_t r = (u + 0x7fffu + ((u >> 16) & 1u)) >> 16;  // RNE
  return (ushort)r;
}

// ---------------- persistent pipelined GEMM, W1-conversion fused (R8 measured-best) ----
// P[M][256] = bf16(h)[M][128] @ bf16(W1cat)[256][128]^T + 0.5*b1
__global__ __launch_bounds__(1024)
void gemm_pipe_kernel(const float* __restrict__ h, const float* __restrict__ W1,
                      const float* __restrict__ b1, ushort* __restrict__ P,
                      int M, int nTiles) {
  __shared__ __align__(16) char ldsraw[132096];
  // layout: A0 16KB | A1 16KB | outLds 33792B | B 64KB   (disjoint, no aliasing)
  char* ldsA0    = ldsraw;
  char* ldsA1    = ldsraw + 16384;
  ushort* outLds = (ushort*)(ldsraw + 32768);       // 64 rows x 264 shorts
  char* ldsB     = ldsraw + 66560;

  const int tid  = threadIdx.x;      // 0..1023
  const int lane = tid & 63;
  const int w    = tid >> 6;         // 0..15

  // --- stage B: W1 fp32 -> bf16, swizzled ds_write (fused cvt_w1) ---
  #pragma unroll
  for (int it = 0; it < 4; ++it) {
    int idx = it * 1024 + tid;              // 8-elem chunk id, 0..4095
    int row = idx >> 4;                     // 0..255
    int c   = idx & 15;                     // chunk of 8 floats
    const float* srcp = (row < HIDDEN) ? (W1 + row * TWO_IN + c * 8)
                                       : (W1 + (row - HIDDEN) * TWO_IN + IN_FEATS + c * 8);
    float4 v0 = *(const float4*)(srcp);
    float4 v1 = *(const float4*)(srcp + 4);
    u16x8 o;
    o[0] = f2bf(v0.x); o[1] = f2bf(v0.y); o[2] = f2bf(v0.z); o[3] = f2bf(v0.w);
    o[4] = f2bf(v1.x); o[5] = f2bf(v1.y); o[6] = f2bf(v1.z); o[7] = f2bf(v1.w);
    *(u16x8*)(ldsB + row * 256 + ((c * 16) ^ ((row & 7) << 4))) = o;
  }

  // --- stage A for first tile into A0 ---
  {
    int m0 = blockIdx.x * TILE_M;
    int row = tid >> 4;                     // 64 rows x 16 chunks = 1024
    int c   = tid & 15;
    int grow = m0 + row;
    float4 v0 = {0, 0, 0, 0}, v1 = {0, 0, 0, 0};
    if (grow < M) {
      const float* srcp = h + (size_t)grow * IN_FEATS + c * 8;
      v0 = *(const float4*)(srcp);
      v1 = *(const float4*)(srcp + 4);
    }
    u16x8 o;
    o[0] = f2bf(v0.x); o[1] = f2bf(v0.y); o[2] = f2bf(v0.z); o[3] = f2bf(v0.w);
    o[4] = f2bf(v1.x); o[5] = f2bf(v1.y); o[6] = f2bf(v1.z); o[7] = f2bf(v1.w);
    *(u16x8*)(ldsA0 + row * 256 + ((c * 16) ^ ((row & 7) << 4))) = o;
  }
  __syncthreads();   // B + A0 staged

  const int wr = w >> 2, wc = w & 3;        // wave tile: 16 rows x 64 cols

  // bias fold: P += 0.5*b1[col & 127]
  float bias[4];
  #pragma unroll
  for (int n = 0; n < 4; ++n) {
    int col = wc * 64 + n * 16 + (lane & 15);
    bias[n] = 0.5f * b1[col & 127];
  }

  int cur = 0;
  for (int t = blockIdx.x; t < nTiles; t += GEMM_BLOCKS) {
    const int m0 = t * TILE_M;
    const int tn = t + GEMM_BLOCKS;
    const bool pf = (tn < nTiles);
    char* ldsAcur = cur ? ldsA1 : ldsA0;
    char* ldsAnxt = cur ? ldsA0 : ldsA1;

    // --- issue prefetch loads for tile t+GEMM_BLOCKS (fp32 -> regs, no wait) ---
    const int prow = tid >> 4;
    const int pc   = tid & 15;
    float4 p0 = {0, 0, 0, 0}, p1 = {0, 0, 0, 0};
    if (pf) {
      int grow = tn * TILE_M + prow;
      if (grow < M) {
        const float* srcp = h + (size_t)grow * IN_FEATS + pc * 8;
        p0 = *(const float4*)(srcp);
        p1 = *(const float4*)(srcp + 4);
      }
    }

    // --- MFMA on A[cur], B ---
    f32x4 acc[4] = {};
    #pragma unroll
    for (int kk = 0; kk < 4; ++kk) {
      bf16x8 af, bfr[4];
      const int kb = kk * 64 + ((lane >> 4) << 4);
      {
        int row = wr * 16 + (lane & 15);
        af = *(const bf16x8*)(ldsAcur + row * 256 + (kb ^ ((row & 7) << 4)));
      }
      #pragma unroll
      for (int n = 0; n < 4; ++n) {
        int row = wc * 64 + n * 16 + (lane & 15);
        bfr[n] = *(const bf16x8*)(ldsB + row * 256 + (kb ^ ((row & 7) << 4)));
      }
      #pragma unroll
      for (int n = 0; n < 4; ++n)
        acc[n] = __builtin_amdgcn_mfma_f32_16x16x32_bf16(af, bfr[n], acc[n], 0, 0, 0);
    }

    __syncthreads();  // B1: prior iter's store-phase finished reading outLds

    // --- acc + bias -> outLds (bf16) ---
    #pragma unroll
    for (int n = 0; n < 4; ++n) {
      int col = wc * 64 + n * 16 + (lane & 15);
      #pragma unroll
      for (int r = 0; r < 4; ++r) {
        int row = wr * 16 + ((lane >> 4) << 2) + r;
        outLds[row * 264 + col] = f2bf(acc[n][r] + bias[n]);
      }
    }

    // --- convert prefetched A and write to the other buffer ---
    if (pf) {
      u16x8 o;
      o[0] = f2bf(p0.x); o[1] = f2bf(p0.y); o[2] = f2bf(p0.z); o[3] = f2bf(p0.w);
      o[4] = f2bf(p1.x); o[5] = f2bf(p1.y); o[6] = f2bf(p1.z); o[7] = f2bf(p1.w);
      *(u16x8*)(ldsAnxt + prow * 256 + ((pc * 16) ^ ((prow & 7) << 4))) = o;
    }

    __syncthreads();  // B2: outLds + A[next] writes visible

    // --- outLds -> P global stores (tile t) ---
    const int mleft = M - m0;
    #pragma unroll
    for (int it = 0; it < 2; ++it) {
      int idx = it * 1024 + tid;            // 16B chunk, 0..2047
      int row = idx >> 5;                   // 32 chunks per 512B row
      int c   = idx & 31;
      if (row < mleft)
        *(u16x8*)((char*)P + (size_t)(m0 + row) * 512 + c * 16) =
            *(const u16x8*)(outLds + row * 264 + c * 8);
    }
    cur ^= 1;
  }
}

// ---------------- edge phase: 16 lanes/edge, 4 edges/wave (R2/R8 measured-best form) ----
__global__ __launch_bounds__(256)
void edge_kernel(const int* __restrict__ src, const int* __restrict__ dst,
                 const ushort* __restrict__ P,
                 const float* __restrict__ W2, const float* __restrict__ b2,
                 float* __restrict__ out, int nE) {
  const int lane = threadIdx.x & 63;
  const int t = lane & 15;          // sublane: feats [t*8, t*8+8)
  const int g = lane >> 4;          // edge slot within wave
  const int wid = blockIdx.x * (blockDim.x >> 6) + (threadIdx.x >> 6);
  const int nw  = gridDim.x * (blockDim.x >> 6);
  const float4 w2a = ((const float4*)W2)[2 * t];
  const float4 w2b = ((const float4*)W2)[2 * t + 1];
  const float b2s = *b2;

  #pragma unroll 2
  for (int e0 = wid * 4; e0 < nE; e0 += nw * 4) {
    int e = e0 + g;
    bool valid = e < nE;
    int ec = valid ? e : nE - 1;
    int s = src[ec], d = dst[ec];
    uint4 pa = *(const uint4*)(P + (size_t)s * 256 + t * 8);
    uint4 pb = *(const uint4*)(P + (size_t)d * 256 + 128 + t * 8);
    float acc;
    acc = fmaxf(bf_lo(pa.x) + bf_lo(pb.x), 0.0f) * w2a.x;
    acc = fmaf(fmaxf(bf_hi(pa.x) + bf_hi(pb.x), 0.0f), w2a.y, acc);
    acc = fmaf(fmaxf(bf_lo(pa.y) + bf_lo(pb.y), 0.0f), w2a.z, acc);
    acc = fmaf(fmaxf(bf_hi(pa.y) + bf_hi(pb.y), 0.0f), w2a.w, acc);
    acc = fmaf(fmaxf(bf_lo(pa.z) + bf_lo(pb.z), 0.0f), w2b.x, acc);
    acc = fmaf(fmaxf(bf_hi(pa.z) + bf_hi(pb.z), 0.0f), w2b.y, acc);
    acc = fmaf(fmaxf(bf_lo(pa.w) + bf_lo(pb.w), 0.0f), w2b.z, acc);
    acc = fmaf(fmaxf(bf_hi(pa.w) + bf_hi(pb.w), 0.0f), w2b.w, acc);
    acc += __shfl_xor(acc, 8);
    acc += __shfl_xor(acc, 4);
    acc += __shfl_xor(acc, 2);
    acc += __shfl_xor(acc, 1);
    if (t == 0 && valid) out[e] = 1.0f / (1.0f + __expf(-(acc + b2s)));
  }
}

extern "C" void kernel_launch(void* const* d_in, const int* in_sizes, int n_in,
                              void* d_out, int out_size, void* d_ws, size_t ws_size,
                              hipStream_t stream) {
  const int*   src = (const int*)d_in[0];
  const int*   dst = (const int*)d_in[1];
  const float* h   = (const float*)d_in[2];
  const float* W1  = (const float*)d_in[3];
  const float* b1  = (const float*)d_in[4];
  const float* W2  = (const float*)d_in[5];
  const float* b2  = (const float*)d_in[6];
  float* out = (float*)d_out;
  const int nE = in_sizes[0];
  const int nN = in_sizes[2] / IN_FEATS;
  const int nTiles = (nN + TILE_M - 1) / TILE_M;

  ushort* P = (ushort*)d_ws;                      // nN*512 B  (~51.2MB)

  hipLaunchKernelGGL(gemm_pipe_kernel, dim3(GEMM_BLOCKS), dim3(1024), 0, stream, h, W1, b1, P, nN, nTiles);
  hipLaunchKernelGGL(edge_kernel, dim3(4096), dim3(256), 0, stream, src, dst, P, W2, b2, out, nE);
}